// Round 13
// baseline (162.159 us; speedup 1.0000x reference)
//
#include <hip/hip_runtime.h>

constexpr int S = 4096, M = 512, E = 16, CC = 128;
constexpr int H1 = 500, H2 = 500, H3 = 2000;
constexpr int TB = 256;   // mmd tile size

// fused: select = x@Wr^T + noise; top2; sel0 output; per-block column partials; zero counters
__global__ void k_route(const float* __restrict__ x, const float* __restrict__ noise,
                        const float* __restrict__ Wr, int* __restrict__ i0, int* __restrict__ i1,
                        float* __restrict__ g0, float* __restrict__ g1,
                        float* __restrict__ sel0, float* __restrict__ selpart,
                        int* __restrict__ counters) {
  if (blockIdx.x == 0 && threadIdx.x < 4) counters[threadIdx.x] = 0;
  int wid = threadIdx.x >> 6, lane = threadIdx.x & 63;
  int s = blockIdx.x * 4 + wid;
  const float* xr = x + (size_t)s * M;
  float xv[8];
#pragma unroll
  for (int c = 0; c < 8; ++c) xv[c] = xr[lane + 64 * c];
  float v[E];
#pragma unroll
  for (int e = 0; e < E; ++e) {
    const float* wr = Wr + (size_t)e * M;
    float acc = 0.f;
#pragma unroll
    for (int c = 0; c < 8; ++c) acc = fmaf(xv[c], wr[lane + 64 * c], acc);
#pragma unroll
    for (int off = 32; off; off >>= 1) acc += __shfl_xor(acc, off);
    v[e] = acc + noise[s * E + e];
  }
  int a0 = 0; float m0 = v[0];
#pragma unroll
  for (int e = 1; e < E; ++e) if (v[e] > m0) { m0 = v[e]; a0 = e; }
  int a1 = -1; float m1 = -3.4e38f;
#pragma unroll
  for (int e = 0; e < E; ++e) if (e != a0 && v[e] > m1) { m1 = v[e]; a1 = e; }
  __shared__ float vsh[4][16];
  if (lane < 16) vsh[wid][lane] = v[lane];
  if (lane == 0) { i0[s] = a0; i1[s] = a1; g0[s] = m0; g1[s] = m1; }
  if (lane < 16) {
    int e = lane;
    sel0[(size_t)s * 32 + e * 2 + 0] = (e == a0 && m0 != 0.f) ? 1.f : 0.f;
    sel0[(size_t)s * 32 + e * 2 + 1] = (e == a1 && m1 != 0.f) ? 1.f : 0.f;
  }
  __syncthreads();
  if (threadIdx.x < 16) {
    int e = threadIdx.x;
    selpart[blockIdx.x * 16 + e] = vsh[0][e] + vsh[1][e] + vsh[2][e] + vsh[3][e];
  }
}

// compact token lists per (e,k), order-preserving (deterministic)
__global__ void k_lists(const int* __restrict__ i0, const int* __restrict__ i1,
                        const float* __restrict__ g0, const float* __restrict__ g1,
                        int* __restrict__ list, int* __restrict__ cnt) {
  int ek = blockIdx.x;
  int k = ek & 1, e = ek >> 1;
  const int* route = k ? i1 : i0;
  const float* gg = k ? g1 : g0;
  __shared__ int base_s;
  __shared__ int wsum[4];
  int t = threadIdx.x;
  int lane = t & 63, w = t >> 6;
  if (t == 0) base_s = 0;
  __syncthreads();
  for (int s0 = 0; s0 < S; s0 += 256) {
    int s = s0 + t;
    bool flag = (route[s] == e) && (gg[s] != 0.f);
    unsigned long long m = __ballot(flag);
    int within = __popcll(m & ((1ull << lane) - 1ull));
    if (lane == 0) wsum[w] = __popcll(m);
    __syncthreads();
    int wbase = base_s;
    for (int i = 0; i < w; ++i) wbase += wsum[i];
    if (flag) list[ek * S + wbase + within] = s;
    __syncthreads();
    if (t == 0) base_s += wsum[0] + wsum[1] + wsum[2] + wsum[3];
    __syncthreads();
  }
  if (t == 0) cnt[ek] = base_s;
}

// 8-way segmented gather partials (by list stride) + elected-last-block reduce -> ei
__global__ void k_gather(const float* __restrict__ x, const int* __restrict__ list,
                         const int* __restrict__ cnt, float* __restrict__ gpart,
                         float* __restrict__ ei, int* __restrict__ counters) {
  int b = blockIdx.x;                  // 1024 = ek(32)*chunk(4)*seg(8)
  int seg = b & 7, chunk = (b >> 3) & 3, ek = b >> 5;
  int t = threadIdx.x;                 // 128
  int d = chunk * 128 + t;
  int nl = cnt[ek];
  const int* lp = list + ek * S;
  float acc = 0.f;
  int q = seg;
  for (; q + 24 < nl; q += 32) {
    int s0 = lp[q], s1 = lp[q + 8], s2 = lp[q + 16], s3 = lp[q + 24];
    acc += x[(size_t)s0 * M + d];
    acc += x[(size_t)s1 * M + d];
    acc += x[(size_t)s2 * M + d];
    acc += x[(size_t)s3 * M + d];
  }
  for (; q < nl; q += 8) acc += x[(size_t)lp[q] * M + d];
  gpart[(size_t)seg * (32 * M) + ek * M + d] = acc;

  // elected last block: fixed-order 8-way reduce -> ei (float4)
  __shared__ int lastflag;
  __syncthreads();
  if (t == 0) {
    __threadfence();
    int old = atomicAdd(&counters[2], 1);
    lastflag = (old == (int)gridDim.x - 1) ? 1 : 0;
  }
  __syncthreads();
  if (!lastflag) return;
  __threadfence();
  const float4* gp4 = (const float4*)gpart;
  float4* ei4 = (float4*)ei;
  for (int i4 = t; i4 < (E * 2 * M) / 4; i4 += 128) {
    float4 a = gp4[i4];
#pragma unroll
    for (int sg = 1; sg < 8; ++sg) {
      float4 bb = gp4[(size_t)sg * ((32 * M) / 4) + i4];
      a.x += bb.x; a.y += bb.y; a.z += bb.z; a.w += bb.w;
    }
    ei4[i4] = a;
  }
}

// generic MLP layer: wave per (e,h) output neuron, both k rows at once
template <int DIN, int HOUT, bool RELU>
__global__ void k_layer(const float* __restrict__ in, const float* __restrict__ W,
                        const float* __restrict__ bias, float* __restrict__ out) {
  int w = (blockIdx.x * blockDim.x + threadIdx.x) >> 6;
  int lane = threadIdx.x & 63;
  if (w >= E * HOUT) return;
  int e = w / HOUT, h = w - e * HOUT;
  const float* wr = W + ((size_t)e * HOUT + h) * DIN;
  const float* in0 = in + (size_t)(e * 2 + 0) * DIN;
  const float* in1 = in + (size_t)(e * 2 + 1) * DIN;
  float a0 = 0.f, a1 = 0.f;
  for (int m = lane; m < DIN; m += 64) {
    float wv = wr[m];
    a0 += wv * in0[m];
    a1 += wv * in1[m];
  }
#pragma unroll
  for (int off = 32; off; off >>= 1) {
    a0 += __shfl_xor(a0, off);
    a1 += __shfl_xor(a1, off);
  }
  if (lane == 0) {
    float bb = bias[e * HOUT + h];
    float o0 = a0 + bb, o1 = a1 + bb;
    if (RELU) { o0 = fmaxf(o0, 0.f); o1 = fmaxf(o1, 0.f); }
    out[(size_t)(e * 2 + 0) * HOUT + h] = o0;
    out[(size_t)(e * 2 + 1) * HOUT + h] = o1;
  }
}

// mid2: blocks 0..nrowblk-1 = row scalars + wpart partials (local diag);
//       block nrowblk = Gram32; block nrowblk+1 = balance;
//       elected last block = cl from wpart + G32.
__global__ __launch_bounds__(256) void k_mid2(const float* __restrict__ eo,
                        const float* __restrict__ selpart,
                        const int* __restrict__ idx1, const int* __restrict__ idx2,
                        const int* __restrict__ i0, const int* __restrict__ i1,
                        const float* __restrict__ g0, const float* __restrict__ g1,
                        float* __restrict__ G32, float* __restrict__ rowg,
                        float* __restrict__ rowa, int* __restrict__ rowe,
                        float* __restrict__ wpart, float* __restrict__ cl,
                        float* __restrict__ outb,
                        int ns, int ncnt, int npad, int nrowblk, int* __restrict__ counters) {
  __shared__ double redd[256];
  __shared__ int lastflag;
  int t = threadIdx.x, blk = blockIdx.x;
  int lane = t & 63, w = t >> 6;

  if (blk < nrowblk) {
    __shared__ float diag[32];
    __shared__ float sw[4][32], sw2[4][32];
    if (t < 32) {
      const float* er = eo + t * CC;
      float s = 0.f;
      for (int d = 0; d < CC; ++d) s = fmaf(er[d], er[d], s);
      diag[t] = s;
    }
    __syncthreads();
    int r = blk * 256 + t;
    float g = 0.f; int ek = 0;
    if (r < ns)        { int tk = idx1[r];      ek = i0[tk] * 2 + 0; g = g0[tk]; }
    else if (r < ncnt) { int tk = idx2[r - ns]; ek = i1[tk] * 2 + 1; g = g1[tk]; }
    if (r < npad) { rowg[r] = g; rowe[r] = ek; rowa[r] = g * g * diag[ek]; }
    float g2 = g * g;
    for (int e = 0; e < 32; ++e) {
      float vw = (ek == e && r < npad) ? g : 0.f;
      float vw2 = (ek == e && r < npad) ? g2 : 0.f;
#pragma unroll
      for (int off = 32; off; off >>= 1) { vw += __shfl_xor(vw, off); vw2 += __shfl_xor(vw2, off); }
      if (lane == 0) { sw[w][e] = vw; sw2[w][e] = vw2; }
    }
    __syncthreads();
    if (t < 32) {
      wpart[blk * 64 + t]      = sw[0][t] + sw[1][t] + sw[2][t] + sw[3][t];
      wpart[blk * 64 + 32 + t] = sw2[0][t] + sw2[1][t] + sw2[2][t] + sw2[3][t];
    }
  } else if (blk == nrowblk) {
    __shared__ float Es[32 * 132];
    for (int i = t; i < 32 * CC; i += 256) Es[(i >> 7) * 132 + (i & 127)] = eo[i];
    __syncthreads();
    for (int p = t; p < 1024; p += 256) {
      int u = p >> 5, v = p & 31;
      float s = 0.f;
#pragma unroll 8
      for (int d = 0; d < CC; ++d) s = fmaf(Es[u * 132 + d], Es[v * 132 + d], s);
      G32[p] = s;
    }
  } else {
    // balance loss (256 threads)
    __shared__ float dpl[16];
    int e2 = t & 15, r0 = t >> 4;
    double acc = 0.0;
    for (int b2 = r0; b2 < 1024; b2 += 16) acc += (double)selpart[b2 * 16 + e2];
    redd[t] = acc;
    __syncthreads();
    for (int off = 128; off >= 16; off >>= 1) { if (t < off) redd[t] += redd[t + off]; __syncthreads(); }
    if (t < 16) dpl[t] = (float)(redd[t] / (double)S);
    __syncthreads();
    double acc2 = 0.0;
    for (int s2 = t; s2 < S; s2 += 256) acc2 += 0.5 * ((double)dpl[i0[s2]] + (double)dpl[i1[s2]]);
    redd[t] = acc2;
    __syncthreads();
    for (int off = 128; off; off >>= 1) { if (t < off) redd[t] += redd[t + off]; __syncthreads(); }
    if (t == 0) outb[0] = (float)(redd[0] / 256.0);
  }

  // elected last block computes cl
  __syncthreads();
  if (t == 0) {
    __threadfence();
    int old = atomicAdd(&counters[1], 1);
    lastflag = (old == nrowblk + 2 - 1) ? 1 : 0;
  }
  __syncthreads();
  if (!lastflag) return;
  __threadfence();
  __shared__ float wf[32], w2f[32];
  if (t < 32) {
    float sw = 0.f, sw2 = 0.f;
    for (int b = 0; b < nrowblk; ++b) { sw += wpart[b * 64 + t]; sw2 += wpart[b * 64 + 32 + t]; }
    wf[t] = sw; w2f[t] = sw2;
  }
  __syncthreads();
  double part = 0.0;
  for (int i = t; i < 1024; i += 256)
    part += (double)wf[i >> 5] * (double)wf[i & 31] * (double)G32[i];
  redd[t] = part;
  __syncthreads();
  for (int off = 128; off; off >>= 1) { if (t < off) redd[t] += redd[t + off]; __syncthreads(); }
  double wGw = redd[0];
  __syncthreads();
  redd[t] = (t < 32) ? (double)w2f[t] * (double)G32[t * 33] : 0.0;
  __syncthreads();
  for (int off = 128; off; off >>= 1) { if (t < off) redd[t] += redd[t + off]; __syncthreads(); }
  if (t == 0) {
    double nn = (double)ncnt;
    double sumd2 = 2.0 * nn * redd[0] - 2.0 * wGw;
    double bw = sumd2 / (nn * nn - nn) / 4.0;
#pragma unroll
    for (int l = 0; l < 5; ++l) cl[l] = (float)(1.0 / (bw * (double)(1 << l)));
  }
}

// fused tail: blocks [0,ntri) = 256x256 mmd tiles; blocks [ntri,+1024) = token output;
//             last mmd block = final reduce
__global__ __launch_bounds__(512) void k_mmd2(const float* __restrict__ rowg,
                      const float* __restrict__ rowa, const int* __restrict__ rowe,
                      const float* __restrict__ G32, const float* __restrict__ cl,
                      const float* __restrict__ eo,
                      const int* __restrict__ i0, const int* __restrict__ i1,
                      const float* __restrict__ g0, const float* __restrict__ g1,
                      float* __restrict__ out, double* __restrict__ bsum,
                      float* __restrict__ out_dist,
                      int ns, int ncnt, int nt, int ntri, int* __restrict__ counters) {
  int b = blockIdx.x, tid = threadIdx.x;
  if (b >= ntri) {
    int idx = (b - ntri) * 512 + tid;
    int s = idx >> 7, d = idx & (CC - 1);
    out[idx] = g0[s] * eo[(i0[s] * 2 + 0) * CC + d] + g1[s] * eo[(i1[s] * 2 + 1) * CC + d];
    return;
  }
  __shared__ float K2[1056];
  __shared__ float gA[264], aA[264], sA[264];
  __shared__ int   eA[264];
  __shared__ float gB[264], aB[264], sB[264];
  __shared__ int   eB[264];
  __shared__ float wred[8];
  __shared__ double redd[512];
  __shared__ int lastflag;

  int bi = 0, rem = b;
  while (rem >= nt - bi) { rem -= nt - bi; ++bi; }
  int bj = bi + rem;
  const int ib = bi * TB, jb = bj * TB;

  float c = cl[4];
  for (int i = tid; i < 1024; i += 512) K2[(i >> 5) * 33 + (i & 31)] = 2.f * c * G32[i];
  if (tid < TB) {
    int r = tid, p = (r & 7) * 33 + (r >> 3);
    int m = ib + r;
    gA[p] = rowg[m]; aA[p] = c * rowa[m]; eA[p] = rowe[m] * 33;
    sA[p] = (m < ns) ? 1.f : (m < ncnt ? -1.f : 0.f);
  } else {
    int r = tid - TB, p = (r & 7) * 33 + (r >> 3);
    int m = jb + r;
    gB[p] = rowg[m]; aB[p] = c * rowa[m]; eB[p] = rowe[m];
    sB[p] = (m < ns) ? 1.f : (m < ncnt ? -1.f : 0.f);
  }
  __syncthreads();

  int ti = tid & 15, tj = tid >> 4;
  float gj[8], Aj[8], sgj[8]; int exj[8];
#pragma unroll
  for (int q = 0; q < 8; ++q) {
    int p = q * 33 + tj;
    gj[q] = gB[p]; Aj[q] = aB[p]; exj[q] = eB[p]; sgj[q] = sB[p];
  }
  float gi[16], Ai[16], sgi[16]; int exi[16];
#pragma unroll
  for (int r = 0; r < 16; ++r) {
    int p = (r & 7) * 33 + ti * 2 + (r >> 3);
    gi[r] = gA[p]; Ai[r] = aA[p]; exi[r] = eA[p]; sgi[r] = sA[p];
  }

  float tsum = 0.f;
#pragma unroll
  for (int r = 0; r < 16; ++r) {
#pragma unroll
    for (int q = 0; q < 8; ++q) {
      float gg = gi[r] * gj[q];
      float arg = fmaf(K2[exi[r] + exj[q]], gg, -(Ai[r] + Aj[q]));
      float tv = __expf(arg);
      float t2 = tv * tv;   float s5 = tv + t2;
      float t4 = t2 * t2;   s5 += t4;
      float t8 = t4 * t4;   s5 += t8;
      float t16 = t8 * t8;  s5 += t16;
      tsum = fmaf(sgi[r] * sgj[q], s5, tsum);
    }
  }
#pragma unroll
  for (int off = 32; off; off >>= 1) tsum += __shfl_xor(tsum, off);
  if ((tid & 63) == 0) wred[tid >> 6] = tsum;
  __syncthreads();
  if (tid == 0) {
    float sblk = 0.f;
#pragma unroll
    for (int w = 0; w < 8; ++w) sblk += wred[w];
    bsum[b] = (double)sblk * ((bi == bj) ? 1.0 : 2.0);
  }

  if (tid == 0) {
    __threadfence();
    int old = atomicAdd(&counters[0], 1);
    lastflag = (old == ntri - 1) ? 1 : 0;
  }
  __syncthreads();
  if (!lastflag) return;
  __threadfence();
  double acc = 0.0;
  for (int i = tid; i < ntri; i += 512) acc += bsum[i];
  redd[tid] = acc;
  __syncthreads();
  for (int off = 256; off; off >>= 1) { if (tid < off) redd[tid] += redd[tid + off]; __syncthreads(); }
  if (tid == 0) out_dist[0] = (float)(-redd[0] / ((double)ns * (double)ns));
}

extern "C" void kernel_launch(void* const* d_in, const int* in_sizes, int n_in,
                              void* d_out, int out_size, void* d_ws, size_t ws_size,
                              hipStream_t stream) {
  const float* x  = (const float*)d_in[0];
  const float* noise = (const float*)d_in[1];
  const float* Wr = (const float*)d_in[2];
  const float* W1 = (const float*)d_in[3];
  const float* b1 = (const float*)d_in[4];
  const float* W2 = (const float*)d_in[5];
  const float* b2 = (const float*)d_in[6];
  const float* W3 = (const float*)d_in[7];
  const float* b3 = (const float*)d_in[8];
  const float* W4 = (const float*)d_in[9];
  const float* b4 = (const float*)d_in[10];
  const int* idx1 = (const int*)d_in[11];
  const int* idx2 = (const int*)d_in[12];
  int ns = in_sizes[11];
  int n = 2 * ns;
  int npad = (n + 255) & ~255;
  int nt = npad / TB;
  int ntri = nt * (nt + 1) / 2;
  int nrowblk = npad / 256;

  char* wp = (char*)d_ws;
  size_t off = 0;
  auto alloc = [&](size_t bytes) -> void* {
    void* p = wp + off;
    off += (bytes + 255) & ~(size_t)255;
    return p;
  };
  int*   i0  = (int*)alloc((size_t)S * 4);
  int*   i1  = (int*)alloc((size_t)S * 4);
  float* g0  = (float*)alloc((size_t)S * 4);
  float* g1  = (float*)alloc((size_t)S * 4);
  float* selpart = (float*)alloc((size_t)1024 * 16 * 4);
  int*   list = (int*)alloc((size_t)32 * S * 4);
  int*   cnt  = (int*)alloc(32 * 4);
  float* gpart = (float*)alloc((size_t)8 * 32 * M * 4);
  float* ei  = (float*)alloc((size_t)E * 2 * M * 4);
  float* h1  = (float*)alloc((size_t)E * 2 * H1 * 4);
  float* h2  = (float*)alloc((size_t)E * 2 * H2 * 4);
  float* h3  = (float*)alloc((size_t)E * 2 * H3 * 4);
  float* eo  = (float*)alloc((size_t)E * 2 * CC * 4);
  float* G32 = (float*)alloc((size_t)1024 * 4);
  float* rowg = (float*)alloc((size_t)npad * 4);
  float* rowa = (float*)alloc((size_t)npad * 4);
  int*   rowe = (int*)alloc((size_t)npad * 4);
  float* wpart = (float*)alloc((size_t)nrowblk * 64 * 4);
  float* cl  = (float*)alloc(8 * 4);
  double* bsum = (double*)alloc((size_t)ntri * 8);
  int* counters = (int*)alloc(256);
  (void)ws_size; (void)n_in; (void)out_size;

  float* out      = (float*)d_out;
  float* out_sel0 = out + (size_t)S * CC;
  float* out_bal  = out + (size_t)S * CC + (size_t)S * E * 2;
  float* out_dist = out_bal + 1;

  k_route<<<S / 4, 256, 0, stream>>>(x, noise, Wr, i0, i1, g0, g1, out_sel0, selpart, counters);
  k_lists<<<32, 256, 0, stream>>>(i0, i1, g0, g1, list, cnt);
  k_gather<<<1024, 128, 0, stream>>>(x, list, cnt, gpart, ei, counters);
  k_layer<M, H1, true><<<(E * H1 + 3) / 4, 256, 0, stream>>>(ei, W1, b1, h1);
  k_layer<H1, H2, true><<<(E * H2 + 3) / 4, 256, 0, stream>>>(h1, W2, b2, h2);
  k_layer<H2, H3, true><<<(E * H3 + 3) / 4, 256, 0, stream>>>(h2, W3, b3, h3);
  k_layer<H3, CC, false><<<(E * CC + 3) / 4, 256, 0, stream>>>(h3, W4, b4, eo);
  k_mid2<<<nrowblk + 2, 256, 0, stream>>>(eo, selpart, idx1, idx2, i0, i1, g0, g1,
                                          G32, rowg, rowa, rowe, wpart, cl, out_bal,
                                          ns, n, npad, nrowblk, counters);
  k_mmd2<<<ntri + (S * CC) / 512, 512, 0, stream>>>(rowg, rowa, rowe, G32, cl, eo,
                                                    i0, i1, g0, g1, out, bsum, out_dist,
                                                    ns, n, nt, ntri, counters);
}